// Round 9
// baseline (258.825 us; speedup 1.0000x reference)
//
#include <hip/hip_runtime.h>
#include <stdint.h>

typedef float f32x4 __attribute__((ext_vector_type(4)));
typedef short s16x8 __attribute__((ext_vector_type(8)));
typedef unsigned short u16x4 __attribute__((ext_vector_type(4)));

#define BB 64
#define NN 512
#define DIN 256
#define DOUT 256
#define HH 4
#define HD 64

__device__ __forceinline__ unsigned short f2b(float f) {
  union { float f; unsigned u; } v; v.f = f;
  unsigned r = v.u + 0x7fffu + ((v.u >> 16) & 1u);
  return (unsigned short)(r >> 16);
}
__device__ __forceinline__ void mfma16(f32x4& acc, s16x8 a, s16x8 b) {
  acc = __builtin_amdgcn_mfma_f32_16x16x32_bf16(a, b, acc, 0, 0, 0);
}
// pack 2 f32 -> u32 of 2 bf16 (RNE); no builtin on gfx950 (T12 recipe)
__device__ __forceinline__ unsigned cvtpk(float lo, float hi) {
  unsigned r;
  asm("v_cvt_pk_bf16_f32 %0, %1, %2" : "=v"(r) : "v"(lo), "v"(hi));
  return r;
}

// ---------------- prep kernels ----------------
__global__ void k_conv(const float* __restrict__ src, unsigned short* __restrict__ dst, int n4) {
  int i = blockIdx.x * blockDim.x + threadIdx.x;
  if (i >= n4) return;
  f32x4 v = ((const f32x4*)src)[i];
  u16x4 o;
  o[0] = f2b(v[0]); o[1] = f2b(v[1]); o[2] = f2b(v[2]); o[3] = f2b(v[3]);
  ((u16x4*)dst)[i] = o;
}

__global__ void k_adjbits(const int* __restrict__ adj, unsigned long long* __restrict__ ab) {
  int row = blockIdx.x;
  int w = threadIdx.x >> 6, lane = threadIdx.x & 63;
  int v = adj[row * NN + w * 64 + lane];
  unsigned long long m = __ballot(v != 0);
  if (lane == 0) ab[row * 8 + w] = m;
}

// ---------------- QKV projection (XCD-locality grid) ----------------
// 1-D grid 6144. bid = t%8 + 8*(c + 12*(t/8)): the 12 chunk-blocks of token-tile t
// land consecutively on XCD t%8 -> x-tile fetched once per XCD, W slices L2-resident.
__global__ __launch_bounds__(256) void k_qkv(
    const unsigned short* __restrict__ xh,
    const unsigned short* __restrict__ wqh,
    const unsigned short* __restrict__ wkh,
    const unsigned short* __restrict__ wvh,
    const float* __restrict__ bq, const float* __restrict__ bk, const float* __restrict__ bv,
    unsigned short* __restrict__ Qb, unsigned short* __restrict__ Kb, unsigned short* __restrict__ Vtb)
{
  __shared__ __align__(16) unsigned char xs[32768];
  __shared__ __align__(16) unsigned char wsl[32768];
  int tid = threadIdx.x, wave = tid >> 6, lane = tid & 63;
  int lr = lane & 15, lk = lane >> 4;
  int bid = blockIdx.x;
  int xcd = bid & 7, rest = bid >> 3;
  int c = rest % 12;
  int t = xcd + 8 * (rest / 12);
  int t0 = t * 64;
  int seg = c >> 2, nb0 = (c & 3) * 64;
  const unsigned short* wh = seg == 0 ? wqh : (seg == 1 ? wkh : wvh);
  const float* bias = seg == 0 ? bq : (seg == 1 ? bk : bv);
  int h = c & 3;

  const unsigned short* xsrc = xh + (size_t)t0 * DIN;
  const unsigned short* wsrc = wh + (size_t)nb0 * DIN;
#pragma unroll
  for (int i = 0; i < 8; ++i) {
    int lin = i * 256 + tid;
    int r = lin >> 5, cc = lin & 31;
    int dst = r * 512 + ((cc ^ (r & 7)) << 4);
    *(s16x8*)(xs + dst)  = *(const s16x8*)(xsrc + lin * 8);
    *(s16x8*)(wsl + dst) = *(const s16x8*)(wsrc + lin * 8);
  }
  __syncthreads();

  f32x4 acc[4] = {};
  if (seg < 2) {
    int chrow = wave * 16 + lr;
#pragma unroll
    for (int k0 = 0; k0 < 8; ++k0) {
      int cg = k0 * 4 + lk;
      s16x8 a = *(const s16x8*)(wsl + chrow * 512 + ((cg ^ (chrow & 7)) << 4));
#pragma unroll
      for (int ct = 0; ct < 4; ++ct) {
        int tr = ct * 16 + lr;
        s16x8 b = *(const s16x8*)(xs + tr * 512 + ((cg ^ (tr & 7)) << 4));
        mfma16(acc[ct], a, b);
      }
    }
    unsigned short* dst = (seg == 0) ? Qb : Kb;
    f32x4 bv4 = *(const f32x4*)(bias + nb0 + wave * 16 + lk * 4);
#pragma unroll
    for (int ct = 0; ct < 4; ++ct) {
      int n_ = t0 + ct * 16 + lr;
      int b_ = n_ >> 9, nn = n_ & 511;
      u16x4 pk;
#pragma unroll
      for (int j = 0; j < 4; ++j) pk[j] = f2b(acc[ct][j] + bv4[j]);
      *(u16x4*)(dst + ((size_t)(b_ * HH + h) * NN + nn) * HD + wave * 16 + lk * 4) = pk;
    }
  } else {
    int tokrow = wave * 16 + lr;
#pragma unroll
    for (int k0 = 0; k0 < 8; ++k0) {
      int cg = k0 * 4 + lk;
      s16x8 a = *(const s16x8*)(xs + tokrow * 512 + ((cg ^ (tokrow & 7)) << 4));
#pragma unroll
      for (int nt = 0; nt < 4; ++nt) {
        int cr = nt * 16 + lr;
        s16x8 b = *(const s16x8*)(wsl + cr * 512 + ((cg ^ (cr & 7)) << 4));
        mfma16(acc[nt], a, b);
      }
    }
    int m0 = t0 + wave * 16 + lk * 4;
    int b_ = m0 >> 9, n0 = m0 & 511;
#pragma unroll
    for (int nt = 0; nt < 4; ++nt) {
      int hd = nt * 16 + lr;
      float bs = bias[nb0 + hd];
      u16x4 pk;
#pragma unroll
      for (int j = 0; j < 4; ++j) pk[j] = f2b(acc[nt][j] + bs);
      *(u16x4*)(Vtb + ((size_t)(b_ * HH + h) * HD + hd) * NN + n0) = pk;
    }
  }
}

// ---------------- attention (double-buffered K/V, async-stage split, 1 barrier/kt) ----------------
// grid 512 (XCD-pair swizzled). 8 waves x 32 q-rows. Per kt: issue kt+1 global loads ->
// regs, compute on buf[kt&1], ds_write buf[kt&1^1] after compute, one barrier.
// S^T = mfma(K, Q); O^T = mfma(V^T, P); P wave-private (no barrier on its round-trip).
__global__ __launch_bounds__(512, 4) void k_attn(
    const unsigned short* __restrict__ Qb, const unsigned short* __restrict__ Kb,
    const unsigned short* __restrict__ Vtb, const unsigned long long* __restrict__ ab,
    unsigned short* __restrict__ att)
{
  __shared__ __align__(16) unsigned char kl[2][8192];   // K tiles, XOR-swizzled
  __shared__ __align__(16) unsigned char vtl[2][8192];  // Vt tiles, XOR-swizzled
  __shared__ __align__(16) unsigned char plb[32768];    // per-wave P [2 sub][16 q][64 keys]

  int tid = threadIdx.x, wave = tid >> 6, lane = tid & 63;
  int lr = lane & 15, lk = lane >> 4;
  int bid = blockIdx.x;
  int g = bid >> 4, r = bid & 15;
  int bh = g * 8 + (r & 7);     // pair of blocks sharing bh differ by 8 -> same XCD
  int qt = r >> 3;
  int h = bh & 3, b_ = bh >> 2;
  const unsigned short* Qp = Qb + (size_t)bh * NN * HD;
  const unsigned short* Kp = Kb + (size_t)bh * NN * HD;
  const unsigned short* Vp = Vtb + (size_t)bh * HD * NN;
  int q0 = qt * 256 + wave * 32;

  s16x8 qa[2][2];
#pragma unroll
  for (int s = 0; s < 2; ++s) {
    qa[s][0] = *(const s16x8*)(Qp + (q0 + s * 16 + lr) * HD + lk * 8);
    qa[s][1] = *(const s16x8*)(Qp + (q0 + s * 16 + lr) * HD + 32 + lk * 8);
  }

  f32x4 oacc[2][4] = {};
  float rs[2] = {0.f, 0.f};
  unsigned char* plw = plb + wave * 4096;
  int sw = (lr & 7) << 4;

  int srow = tid >> 3, scol = tid & 7;
  int sdst = srow * 128 + ((scol * 16) ^ ((srow & 7) << 4));
  const unsigned short* ksrc = Kp + srow * HD + scol * 8;
  const unsigned short* vsrc = Vp + srow * NN + scol * 8;

  // prologue: stage kt=0
  *(s16x8*)(kl[0] + sdst)  = *(const s16x8*)ksrc;
  *(s16x8*)(vtl[0] + sdst) = *(const s16x8*)vsrc;
  __syncthreads();

#pragma unroll
  for (int kt = 0; kt < 8; ++kt) {
    unsigned char* klc = kl[kt & 1];
    unsigned char* vtc = vtl[kt & 1];
    // issue next-tile loads early (latency hides under this tile's compute)
    s16x8 gk, gv;
    if (kt < 7) {
      gk = *(const s16x8*)(ksrc + (kt + 1) * 64 * HD);
      gv = *(const s16x8*)(vsrc + (kt + 1) * 64);
    }
    unsigned long long abr[2];
#pragma unroll
    for (int s = 0; s < 2; ++s) abr[s] = ab[(size_t)(q0 + s * 16 + lr) * 8 + kt];

#pragma unroll
    for (int s = 0; s < 2; ++s) {
#pragma unroll
      for (int ks = 0; ks < 4; ++ks) {
        int key = ks * 16 + lr;
        s16x8 kb0 = *(const s16x8*)(klc + key * 128 + ((lk * 16) ^ ((key & 7) << 4)));
        s16x8 kb1 = *(const s16x8*)(klc + key * 128 + ((64 + lk * 16) ^ ((key & 7) << 4)));
        f32x4 sx = {};
        mfma16(sx, kb0, qa[s][0]);   // S^T: rows key=16ks+4lk+j, col q=lr
        mfma16(sx, kb1, qa[s][1]);
        float p[4];
#pragma unroll
        for (int j = 0; j < 4; ++j)
          p[j] = ((abr[s] >> (ks * 16 + lk * 4 + j)) & 1ULL) ? __expf(sx[j] * 0.125f) : 0.0f;
        unsigned w0 = cvtpk(p[0], p[1]);
        unsigned w1 = cvtpk(p[2], p[3]);
        union { unsigned u; float f; } t0, t1, t2, t3;
        t0.u = w0 << 16; t1.u = w0 & 0xffff0000u;
        t2.u = w1 << 16; t3.u = w1 & 0xffff0000u;
        rs[s] += (t0.f + t1.f) + (t2.f + t3.f);
        uint2 pw; pw.x = w0; pw.y = w1;
        *(uint2*)(plw + s * 2048 + lr * 128 + ((ks * 32 + lk * 8) ^ sw)) = pw;
      }
    }
    // P wave-private: compiler orders plb store->load with lgkmcnt
#pragma unroll
    for (int s = 0; s < 2; ++s) {
      s16x8 pa0 = *(const s16x8*)(plw + s * 2048 + lr * 128 + ((lk * 16) ^ sw));
      s16x8 pa1 = *(const s16x8*)(plw + s * 2048 + lr * 128 + ((64 + lk * 16) ^ sw));
#pragma unroll
      for (int dt = 0; dt < 4; ++dt) {
        int d = dt * 16 + lr;
        s16x8 vb0 = *(const s16x8*)(vtc + d * 128 + ((lk * 16) ^ ((d & 7) << 4)));
        s16x8 vb1 = *(const s16x8*)(vtc + d * 128 + ((64 + lk * 16) ^ ((d & 7) << 4)));
        mfma16(oacc[s][dt], vb0, pa0);  // O^T: rows d=dt*16+4lk+j, col q=lr
        mfma16(oacc[s][dt], vb1, pa1);
      }
    }
    if (kt < 7) {
      // write next tile into the other buffer (nobody reads it this kt)
      *(s16x8*)(kl[(kt & 1) ^ 1] + sdst)  = gk;
      *(s16x8*)(vtl[(kt & 1) ^ 1] + sdst) = gv;
      __syncthreads();
    }
  }

#pragma unroll
  for (int s = 0; s < 2; ++s) {
    float v = rs[s];
    v += __shfl_xor(v, 16);
    v += __shfl_xor(v, 32);
    float rinv = 1.0f / v;
    int n_ = q0 + s * 16 + lr;
#pragma unroll
    for (int dt = 0; dt < 4; ++dt) {
      uint2 ow;
      ow.x = cvtpk(oacc[s][dt][0] * rinv, oacc[s][dt][1] * rinv);
      ow.y = cvtpk(oacc[s][dt][2] * rinv, oacc[s][dt][3] * rinv);
      *(uint2*)(att + ((size_t)(b_ * NN + n_) * DOUT) + h * HD + dt * 16 + lk * 4) = ow;
    }
  }
}

// ---------------- output projection (XCD-locality grid) ----------------
// 1-D grid 2048. bid = t%8 + 8*(c + 4*(t/8)): 4 chunk-blocks of a token-tile on one XCD.
__global__ __launch_bounds__(256) void k_out(
    const unsigned short* __restrict__ att, const unsigned short* __restrict__ woh,
    const float* __restrict__ bo, float* __restrict__ out)
{
  __shared__ __align__(16) unsigned char as_[32768];
  __shared__ __align__(16) unsigned char wsl[32768];
  int tid = threadIdx.x, wave = tid >> 6, lane = tid & 63;
  int lr = lane & 15, lk = lane >> 4;
  int bid = blockIdx.x;
  int xcd = bid & 7, rest = bid >> 3;
  int c = rest & 3;
  int t = xcd + 8 * (rest >> 2);
  int t0 = t * 64;
  int nb0 = c * 64;

  const unsigned short* asrc = att + (size_t)t0 * DOUT;
  const unsigned short* wsrc = woh + (size_t)nb0 * DOUT;
#pragma unroll
  for (int i = 0; i < 8; ++i) {
    int lin = i * 256 + tid;
    int r = lin >> 5, cc = lin & 31;
    int dst = r * 512 + ((cc ^ (r & 7)) << 4);
    *(s16x8*)(as_ + dst) = *(const s16x8*)(asrc + lin * 8);
    *(s16x8*)(wsl + dst) = *(const s16x8*)(wsrc + lin * 8);
  }
  __syncthreads();

  f32x4 acc[4] = {};
  int chrow = wave * 16 + lr;
#pragma unroll
  for (int k0 = 0; k0 < 8; ++k0) {
    int cg = k0 * 4 + lk;
    s16x8 a = *(const s16x8*)(wsl + chrow * 512 + ((cg ^ (chrow & 7)) << 4));
#pragma unroll
    for (int ct = 0; ct < 4; ++ct) {
      int tr = ct * 16 + lr;
      s16x8 b = *(const s16x8*)(as_ + tr * 512 + ((cg ^ (tr & 7)) << 4));
      mfma16(acc[ct], a, b);
    }
  }
  f32x4 bv4 = *(const f32x4*)(bo + nb0 + wave * 16 + lk * 4);
#pragma unroll
  for (int ct = 0; ct < 4; ++ct) {
    int m = t0 + ct * 16 + lr;
    f32x4 o = acc[ct] + bv4;
    *(f32x4*)(out + (size_t)m * DOUT + nb0 + wave * 16 + lk * 4) = o;
  }
}

extern "C" void kernel_launch(void* const* d_in, const int* in_sizes, int n_in,
                              void* d_out, int out_size, void* d_ws, size_t ws_size,
                              hipStream_t stream) {
  const float* x  = (const float*)d_in[0];
  const int*   adj = (const int*)d_in[1];
  const float* wq = (const float*)d_in[2];
  const float* bq = (const float*)d_in[3];
  const float* wk = (const float*)d_in[4];
  const float* bk = (const float*)d_in[5];
  const float* wv = (const float*)d_in[6];
  const float* bv = (const float*)d_in[7];
  const float* wo = (const float*)d_in[8];
  const float* bo = (const float*)d_in[9];
  float* out = (float*)d_out;

  char* ws = (char*)d_ws;
  size_t off = 0;
  auto carve = [&](size_t bytes) -> char* {
    off = (off + 255) & ~(size_t)255;
    char* p = ws + off;
    off += bytes;
    return p;
  };
  unsigned short* xh   = (unsigned short*)carve((size_t)BB * NN * DIN * 2);
  unsigned short* wqh  = (unsigned short*)carve((size_t)DOUT * DIN * 2);
  unsigned short* wkh  = (unsigned short*)carve((size_t)DOUT * DIN * 2);
  unsigned short* wvh  = (unsigned short*)carve((size_t)DOUT * DIN * 2);
  unsigned short* woh  = (unsigned short*)carve((size_t)DOUT * DOUT * 2);
  unsigned long long* abits = (unsigned long long*)carve((size_t)NN * 8 * 8);
  unsigned short* Qb   = (unsigned short*)carve((size_t)BB * HH * NN * HD * 2);
  unsigned short* Kb   = (unsigned short*)carve((size_t)BB * HH * NN * HD * 2);
  unsigned short* Vtb  = (unsigned short*)carve((size_t)BB * HH * HD * NN * 2);
  unsigned short* attb = (unsigned short*)carve((size_t)BB * NN * DOUT * 2);

  k_conv<<<dim3(8192), 256, 0, stream>>>(x, xh, (BB * NN * DIN) / 4);
  k_conv<<<dim3(64), 256, 0, stream>>>(wq, wqh, (DOUT * DIN) / 4);
  k_conv<<<dim3(64), 256, 0, stream>>>(wk, wkh, (DOUT * DIN) / 4);
  k_conv<<<dim3(64), 256, 0, stream>>>(wv, wvh, (DOUT * DIN) / 4);
  k_conv<<<dim3(64), 256, 0, stream>>>(wo, woh, (DOUT * DOUT) / 4);
  k_adjbits<<<dim3(512), 512, 0, stream>>>(adj, abits);
  k_qkv<<<dim3(6144), 256, 0, stream>>>(xh, wqh, wkh, wvh, bq, bk, bv, Qb, Kb, Vtb);
  k_attn<<<dim3(512), 512, 0, stream>>>(Qb, Kb, Vtb, abits, attb);
  k_out<<<dim3(2048), 256, 0, stream>>>(attb, woh, bo, out);
}

// Round 10
// 201.122 us; speedup vs baseline: 1.2869x; 1.2869x over previous
//
#include <hip/hip_runtime.h>
#include <stdint.h>

typedef float f32x4 __attribute__((ext_vector_type(4)));
typedef short s16x8 __attribute__((ext_vector_type(8)));
typedef unsigned short u16x4 __attribute__((ext_vector_type(4)));

#define BB 64
#define NN 512
#define DIN 256
#define DOUT 256
#define HH 4
#define HD 64

__device__ __forceinline__ unsigned short f2b(float f) {
  union { float f; unsigned u; } v; v.f = f;
  unsigned r = v.u + 0x7fffu + ((v.u >> 16) & 1u);
  return (unsigned short)(r >> 16);
}
__device__ __forceinline__ void mfma16(f32x4& acc, s16x8 a, s16x8 b) {
  acc = __builtin_amdgcn_mfma_f32_16x16x32_bf16(a, b, acc, 0, 0, 0);
}
// pack 2 f32 -> u32 of 2 bf16 (RNE); no builtin on gfx950 (T12 recipe)
__device__ __forceinline__ unsigned cvtpk(float lo, float hi) {
  unsigned r;
  asm("v_cvt_pk_bf16_f32 %0, %1, %2" : "=v"(r) : "v"(lo), "v"(hi));
  return r;
}

// ---------------- prep kernels ----------------
__global__ void k_conv(const float* __restrict__ src, unsigned short* __restrict__ dst, int n4) {
  int i = blockIdx.x * blockDim.x + threadIdx.x;
  if (i >= n4) return;
  f32x4 v = ((const f32x4*)src)[i];
  u16x4 o;
  o[0] = f2b(v[0]); o[1] = f2b(v[1]); o[2] = f2b(v[2]); o[3] = f2b(v[3]);
  ((u16x4*)dst)[i] = o;
}

__global__ void k_adjbits(const int* __restrict__ adj, unsigned long long* __restrict__ ab) {
  int row = blockIdx.x;
  int w = threadIdx.x >> 6, lane = threadIdx.x & 63;
  int v = adj[row * NN + w * 64 + lane];
  unsigned long long m = __ballot(v != 0);
  if (lane == 0) ab[row * 8 + w] = m;
}

// ---------------- QKV projection (round-5/6-measured 2D grid) ----------------
__global__ __launch_bounds__(256) void k_qkv(
    const unsigned short* __restrict__ xh,
    const unsigned short* __restrict__ wqh,
    const unsigned short* __restrict__ wkh,
    const unsigned short* __restrict__ wvh,
    const float* __restrict__ bq, const float* __restrict__ bk, const float* __restrict__ bv,
    unsigned short* __restrict__ Qb, unsigned short* __restrict__ Kb, unsigned short* __restrict__ Vtb)
{
  __shared__ __align__(16) unsigned char xs[32768];
  __shared__ __align__(16) unsigned char wsl[32768];
  int tid = threadIdx.x, wave = tid >> 6, lane = tid & 63;
  int lr = lane & 15, lk = lane >> 4;
  int t0 = blockIdx.x * 64;
  int by = blockIdx.y, seg = by >> 2, nb0 = (by & 3) * 64;
  const unsigned short* wh = seg == 0 ? wqh : (seg == 1 ? wkh : wvh);
  const float* bias = seg == 0 ? bq : (seg == 1 ? bk : bv);
  int h = by & 3;

  const unsigned short* xsrc = xh + (size_t)t0 * DIN;
  const unsigned short* wsrc = wh + (size_t)nb0 * DIN;
#pragma unroll
  for (int i = 0; i < 8; ++i) {
    int lin = i * 256 + tid;
    int r = lin >> 5, cc = lin & 31;
    int dst = r * 512 + ((cc ^ (r & 7)) << 4);
    *(s16x8*)(xs + dst)  = *(const s16x8*)(xsrc + lin * 8);
    *(s16x8*)(wsl + dst) = *(const s16x8*)(wsrc + lin * 8);
  }
  __syncthreads();

  f32x4 acc[4] = {};
  if (seg < 2) {
    int chrow = wave * 16 + lr;
#pragma unroll
    for (int k0 = 0; k0 < 8; ++k0) {
      int cg = k0 * 4 + lk;
      s16x8 a = *(const s16x8*)(wsl + chrow * 512 + ((cg ^ (chrow & 7)) << 4));
#pragma unroll
      for (int ct = 0; ct < 4; ++ct) {
        int tr = ct * 16 + lr;
        s16x8 b = *(const s16x8*)(xs + tr * 512 + ((cg ^ (tr & 7)) << 4));
        mfma16(acc[ct], a, b);
      }
    }
    unsigned short* dst = (seg == 0) ? Qb : Kb;
    f32x4 bv4 = *(const f32x4*)(bias + nb0 + wave * 16 + lk * 4);
#pragma unroll
    for (int ct = 0; ct < 4; ++ct) {
      int n_ = t0 + ct * 16 + lr;
      int b_ = n_ >> 9, nn = n_ & 511;
      u16x4 pk;
#pragma unroll
      for (int j = 0; j < 4; ++j) pk[j] = f2b(acc[ct][j] + bv4[j]);
      *(u16x4*)(dst + ((size_t)(b_ * HH + h) * NN + nn) * HD + wave * 16 + lk * 4) = pk;
    }
  } else {
    int tokrow = wave * 16 + lr;
#pragma unroll
    for (int k0 = 0; k0 < 8; ++k0) {
      int cg = k0 * 4 + lk;
      s16x8 a = *(const s16x8*)(xs + tokrow * 512 + ((cg ^ (tokrow & 7)) << 4));
#pragma unroll
      for (int nt = 0; nt < 4; ++nt) {
        int cr = nt * 16 + lr;
        s16x8 b = *(const s16x8*)(wsl + cr * 512 + ((cg ^ (cr & 7)) << 4));
        mfma16(acc[nt], a, b);
      }
    }
    int m0 = t0 + wave * 16 + lk * 4;
    int b_ = m0 >> 9, n0 = m0 & 511;
#pragma unroll
    for (int nt = 0; nt < 4; ++nt) {
      int hd = nt * 16 + lr;
      float bs = bias[nb0 + hd];
      u16x4 pk;
#pragma unroll
      for (int j = 0; j < 4; ++j) pk[j] = f2b(acc[nt][j] + bs);
      *(u16x4*)(Vtb + ((size_t)(b_ * HH + h) * HD + hd) * NN + n0) = pk;
    }
  }
}

// ---------------- attention (8-wave, dbuf K/V, spill-aware) ----------------
// grid 512 (XCD-pair swizzled). 8 waves x 32 q-rows. launch_bounds(512,2):
// LDS (64KB) caps at 2 blocks/CU anyway; relaxed bound gives the allocator
// headroom (round 9: (512,4) -> 64 VGPR + 170MB scratch traffic = regression).
// gk/gv prefetch issued BETWEEN QK^T and PV phases: live range spans only PV.
__global__ __launch_bounds__(512, 2) void k_attn(
    const unsigned short* __restrict__ Qb, const unsigned short* __restrict__ Kb,
    const unsigned short* __restrict__ Vtb, const unsigned long long* __restrict__ ab,
    unsigned short* __restrict__ att)
{
  __shared__ __align__(16) unsigned char kl[2][8192];   // K tiles, XOR-swizzled
  __shared__ __align__(16) unsigned char vtl[2][8192];  // Vt tiles, XOR-swizzled
  __shared__ __align__(16) unsigned char plb[32768];    // per-wave P [2 sub][16 q][64 keys]

  int tid = threadIdx.x, wave = tid >> 6, lane = tid & 63;
  int lr = lane & 15, lk = lane >> 4;
  int bid = blockIdx.x;
  int g = bid >> 4, r = bid & 15;
  int bh = g * 8 + (r & 7);     // pair of blocks sharing bh differ by 8 -> same XCD
  int qt = r >> 3;
  int h = bh & 3, b_ = bh >> 2;
  const unsigned short* Qp = Qb + (size_t)bh * NN * HD;
  const unsigned short* Kp = Kb + (size_t)bh * NN * HD;
  const unsigned short* Vp = Vtb + (size_t)bh * HD * NN;
  int q0 = qt * 256 + wave * 32;

  s16x8 qa[2][2];
#pragma unroll
  for (int s = 0; s < 2; ++s) {
    qa[s][0] = *(const s16x8*)(Qp + (q0 + s * 16 + lr) * HD + lk * 8);
    qa[s][1] = *(const s16x8*)(Qp + (q0 + s * 16 + lr) * HD + 32 + lk * 8);
  }

  f32x4 oacc[2][4] = {};
  float rs[2] = {0.f, 0.f};
  unsigned char* plw = plb + wave * 4096;
  int sw = (lr & 7) << 4;

  int srow = tid >> 3, scol = tid & 7;
  int sdst = srow * 128 + ((scol * 16) ^ ((srow & 7) << 4));
  const unsigned short* ksrc = Kp + srow * HD + scol * 8;
  const unsigned short* vsrc = Vp + srow * NN + scol * 8;

  // prologue: stage kt=0
  *(s16x8*)(kl[0] + sdst)  = *(const s16x8*)ksrc;
  *(s16x8*)(vtl[0] + sdst) = *(const s16x8*)vsrc;
  __syncthreads();

#pragma unroll
  for (int kt = 0; kt < 8; ++kt) {
    unsigned char* klc = kl[kt & 1];
    unsigned char* vtc = vtl[kt & 1];
    unsigned long long abr[2];
#pragma unroll
    for (int s = 0; s < 2; ++s) abr[s] = ab[(size_t)(q0 + s * 16 + lr) * 8 + kt];

    // ---- QK^T + softmax-exp + P store (gk/gv not yet live) ----
#pragma unroll
    for (int s = 0; s < 2; ++s) {
#pragma unroll
      for (int ks = 0; ks < 4; ++ks) {
        int key = ks * 16 + lr;
        s16x8 kb0 = *(const s16x8*)(klc + key * 128 + ((lk * 16) ^ ((key & 7) << 4)));
        s16x8 kb1 = *(const s16x8*)(klc + key * 128 + ((64 + lk * 16) ^ ((key & 7) << 4)));
        f32x4 sx = {};
        mfma16(sx, kb0, qa[s][0]);   // S^T: rows key=16ks+4lk+j, col q=lr
        mfma16(sx, kb1, qa[s][1]);
        float p[4];
#pragma unroll
        for (int j = 0; j < 4; ++j)
          p[j] = ((abr[s] >> (ks * 16 + lk * 4 + j)) & 1ULL) ? __expf(sx[j] * 0.125f) : 0.0f;
        unsigned w0 = cvtpk(p[0], p[1]);
        unsigned w1 = cvtpk(p[2], p[3]);
        union { unsigned u; float f; } t0, t1, t2, t3;
        t0.u = w0 << 16; t1.u = w0 & 0xffff0000u;
        t2.u = w1 << 16; t3.u = w1 & 0xffff0000u;
        rs[s] += (t0.f + t1.f) + (t2.f + t3.f);
        uint2 pw; pw.x = w0; pw.y = w1;
        *(uint2*)(plw + s * 2048 + lr * 128 + ((ks * 32 + lk * 8) ^ sw)) = pw;
      }
    }

    // ---- issue next-tile prefetch; latency hides under PV below ----
    s16x8 gk, gv;
    if (kt < 7) {
      gk = *(const s16x8*)(ksrc + (kt + 1) * 64 * HD);
      gv = *(const s16x8*)(vsrc + (kt + 1) * 64);
    }

    // ---- PV (P wave-private: compiler orders plb store->load via lgkmcnt) ----
#pragma unroll
    for (int s = 0; s < 2; ++s) {
      s16x8 pa0 = *(const s16x8*)(plw + s * 2048 + lr * 128 + ((lk * 16) ^ sw));
      s16x8 pa1 = *(const s16x8*)(plw + s * 2048 + lr * 128 + ((64 + lk * 16) ^ sw));
#pragma unroll
      for (int dt = 0; dt < 4; ++dt) {
        int d = dt * 16 + lr;
        s16x8 vb0 = *(const s16x8*)(vtc + d * 128 + ((lk * 16) ^ ((d & 7) << 4)));
        s16x8 vb1 = *(const s16x8*)(vtc + d * 128 + ((64 + lk * 16) ^ ((d & 7) << 4)));
        mfma16(oacc[s][dt], vb0, pa0);  // O^T: rows d=dt*16+4lk+j, col q=lr
        mfma16(oacc[s][dt], vb1, pa1);
      }
    }
    if (kt < 7) {
      *(s16x8*)(kl[(kt & 1) ^ 1] + sdst)  = gk;
      *(s16x8*)(vtl[(kt & 1) ^ 1] + sdst) = gv;
      __syncthreads();
    }
  }

#pragma unroll
  for (int s = 0; s < 2; ++s) {
    float v = rs[s];
    v += __shfl_xor(v, 16);
    v += __shfl_xor(v, 32);
    float rinv = 1.0f / v;
    int n_ = q0 + s * 16 + lr;
#pragma unroll
    for (int dt = 0; dt < 4; ++dt) {
      uint2 ow;
      ow.x = cvtpk(oacc[s][dt][0] * rinv, oacc[s][dt][1] * rinv);
      ow.y = cvtpk(oacc[s][dt][2] * rinv, oacc[s][dt][3] * rinv);
      *(uint2*)(att + ((size_t)(b_ * NN + n_) * DOUT) + h * HD + dt * 16 + lk * 4) = ow;
    }
  }
}

// ---------------- output projection (round-5/6-measured 2D grid) ----------------
__global__ __launch_bounds__(256) void k_out(
    const unsigned short* __restrict__ att, const unsigned short* __restrict__ woh,
    const float* __restrict__ bo, float* __restrict__ out)
{
  __shared__ __align__(16) unsigned char as_[32768];
  __shared__ __align__(16) unsigned char wsl[32768];
  int tid = threadIdx.x, wave = tid >> 6, lane = tid & 63;
  int lr = lane & 15, lk = lane >> 4;
  int t0 = blockIdx.x * 64;
  int nb0 = blockIdx.y * 64;

  const unsigned short* asrc = att + (size_t)t0 * DOUT;
  const unsigned short* wsrc = woh + (size_t)nb0 * DOUT;
#pragma unroll
  for (int i = 0; i < 8; ++i) {
    int lin = i * 256 + tid;
    int r = lin >> 5, cc = lin & 31;
    int dst = r * 512 + ((cc ^ (r & 7)) << 4);
    *(s16x8*)(as_ + dst) = *(const s16x8*)(asrc + lin * 8);
    *(s16x8*)(wsl + dst) = *(const s16x8*)(wsrc + lin * 8);
  }
  __syncthreads();

  f32x4 acc[4] = {};
  int chrow = wave * 16 + lr;
#pragma unroll
  for (int k0 = 0; k0 < 8; ++k0) {
    int cg = k0 * 4 + lk;
    s16x8 a = *(const s16x8*)(wsl + chrow * 512 + ((cg ^ (chrow & 7)) << 4));
#pragma unroll
    for (int ct = 0; ct < 4; ++ct) {
      int tr = ct * 16 + lr;
      s16x8 b = *(const s16x8*)(as_ + tr * 512 + ((cg ^ (tr & 7)) << 4));
      mfma16(acc[ct], a, b);
    }
  }
  f32x4 bv4 = *(const f32x4*)(bo + nb0 + wave * 16 + lk * 4);
#pragma unroll
  for (int ct = 0; ct < 4; ++ct) {
    int m = t0 + ct * 16 + lr;
    f32x4 o = acc[ct] + bv4;
    *(f32x4*)(out + (size_t)m * DOUT + nb0 + wave * 16 + lk * 4) = o;
  }
}

extern "C" void kernel_launch(void* const* d_in, const int* in_sizes, int n_in,
                              void* d_out, int out_size, void* d_ws, size_t ws_size,
                              hipStream_t stream) {
  const float* x  = (const float*)d_in[0];
  const int*   adj = (const int*)d_in[1];
  const float* wq = (const float*)d_in[2];
  const float* bq = (const float*)d_in[3];
  const float* wk = (const float*)d_in[4];
  const float* bk = (const float*)d_in[5];
  const float* wv = (const float*)d_in[6];
  const float* bv = (const float*)d_in[7];
  const float* wo = (const float*)d_in[8];
  const float* bo = (const float*)d_in[9];
  float* out = (float*)d_out;

  char* ws = (char*)d_ws;
  size_t off = 0;
  auto carve = [&](size_t bytes) -> char* {
    off = (off + 255) & ~(size_t)255;
    char* p = ws + off;
    off += bytes;
    return p;
  };
  unsigned short* xh   = (unsigned short*)carve((size_t)BB * NN * DIN * 2);
  unsigned short* wqh  = (unsigned short*)carve((size_t)DOUT * DIN * 2);
  unsigned short* wkh  = (unsigned short*)carve((size_t)DOUT * DIN * 2);
  unsigned short* wvh  = (unsigned short*)carve((size_t)DOUT * DIN * 2);
  unsigned short* woh  = (unsigned short*)carve((size_t)DOUT * DOUT * 2);
  unsigned long long* abits = (unsigned long long*)carve((size_t)NN * 8 * 8);
  unsigned short* Qb   = (unsigned short*)carve((size_t)BB * HH * NN * HD * 2);
  unsigned short* Kb   = (unsigned short*)carve((size_t)BB * HH * NN * HD * 2);
  unsigned short* Vtb  = (unsigned short*)carve((size_t)BB * HH * HD * NN * 2);
  unsigned short* attb = (unsigned short*)carve((size_t)BB * NN * DOUT * 2);

  k_conv<<<dim3(8192), 256, 0, stream>>>(x, xh, (BB * NN * DIN) / 4);
  k_conv<<<dim3(64), 256, 0, stream>>>(wq, wqh, (DOUT * DIN) / 4);
  k_conv<<<dim3(64), 256, 0, stream>>>(wk, wkh, (DOUT * DIN) / 4);
  k_conv<<<dim3(64), 256, 0, stream>>>(wv, wvh, (DOUT * DIN) / 4);
  k_conv<<<dim3(64), 256, 0, stream>>>(wo, woh, (DOUT * DOUT) / 4);
  k_adjbits<<<dim3(512), 512, 0, stream>>>(adj, abits);
  k_qkv<<<dim3(512, 12), 256, 0, stream>>>(xh, wqh, wkh, wvh, bq, bk, bv, Qb, Kb, Vtb);
  k_attn<<<dim3(512), 512, 0, stream>>>(Qb, Kb, Vtb, abits, attb);
  k_out<<<dim3(512, 4), 256, 0, stream>>>(attb, woh, bo, out);
}

// Round 11
// 181.515 us; speedup vs baseline: 1.4259x; 1.1080x over previous
//
#include <hip/hip_runtime.h>
#include <stdint.h>

typedef float f32x4 __attribute__((ext_vector_type(4)));
typedef short s16x8 __attribute__((ext_vector_type(8)));
typedef unsigned short u16x4 __attribute__((ext_vector_type(4)));
typedef unsigned int u32x4 __attribute__((ext_vector_type(4)));

#define BB 64
#define NN 512
#define DIN 256
#define DOUT 256
#define HH 4
#define HD 64

__device__ __forceinline__ unsigned short f2b(float f) {
  union { float f; unsigned u; } v; v.f = f;
  unsigned r = v.u + 0x7fffu + ((v.u >> 16) & 1u);
  return (unsigned short)(r >> 16);
}
__device__ __forceinline__ void mfma16(f32x4& acc, s16x8 a, s16x8 b) {
  acc = __builtin_amdgcn_mfma_f32_16x16x32_bf16(a, b, acc, 0, 0, 0);
}
// pack 2 f32 -> u32 of 2 bf16 (RNE, src0 in low 16); no builtin on gfx950
__device__ __forceinline__ unsigned cvtpk(float lo, float hi) {
  unsigned r;
  asm("v_cvt_pk_bf16_f32 %0, %1, %2" : "=v"(r) : "v"(lo), "v"(hi));
  return r;
}

// ---------------- prep kernels ----------------
// all 4 weight matrices in one launch (grid 256: 64 blocks per matrix)
__global__ void k_wconv(const float* __restrict__ s0, const float* __restrict__ s1,
                        const float* __restrict__ s2, const float* __restrict__ s3,
                        unsigned short* __restrict__ d0, unsigned short* __restrict__ d1,
                        unsigned short* __restrict__ d2, unsigned short* __restrict__ d3) {
  int b = blockIdx.x;
  int mat = b >> 6;
  int i = (b & 63) * 256 + threadIdx.x;   // f32x4 index, 16384 per matrix
  const float* s = mat == 0 ? s0 : mat == 1 ? s1 : mat == 2 ? s2 : s3;
  unsigned short* d = mat == 0 ? d0 : mat == 1 ? d1 : mat == 2 ? d2 : d3;
  f32x4 v = ((const f32x4*)s)[i];
  u16x4 o;
  o[0] = f2b(v[0]); o[1] = f2b(v[1]); o[2] = f2b(v[2]); o[3] = f2b(v[3]);
  ((u16x4*)d)[i] = o;
}

__global__ void k_adjbits(const int* __restrict__ adj, unsigned long long* __restrict__ ab) {
  int row = blockIdx.x;
  int w = threadIdx.x >> 6, lane = threadIdx.x & 63;
  int v = adj[row * NN + w * 64 + lane];
  unsigned long long m = __ballot(v != 0);
  if (lane == 0) ab[row * 8 + w] = m;
}

// ---------------- QKV projection (x staged ONCE, 12 chunk loop, reg-prefetched W) ----------------
// grid 512: block = 64-token x-tile. Stage x (f32->bf16 in staging) once; loop the 12
// (seg,head) 64-col weight chunks with gw-register prefetch (2 barriers/chunk).
// Fragment/epilogue math identical to the measured round-3..10 kernel.
__global__ __launch_bounds__(256, 2) void k_qkv(
    const float* __restrict__ x,
    const unsigned short* __restrict__ wqh,
    const unsigned short* __restrict__ wkh,
    const unsigned short* __restrict__ wvh,
    const float* __restrict__ bq, const float* __restrict__ bk, const float* __restrict__ bv,
    unsigned short* __restrict__ Qb, unsigned short* __restrict__ Kb, unsigned short* __restrict__ Vtb)
{
  __shared__ __align__(16) unsigned char xs[32768];
  __shared__ __align__(16) unsigned char wsl[32768];
  int tid = threadIdx.x, wave = tid >> 6, lane = tid & 63;
  int lr = lane & 15, lk = lane >> 4;
  int t0 = blockIdx.x * 64;

  const float* xsrc = x + (size_t)t0 * DIN;
#pragma unroll
  for (int i = 0; i < 8; ++i) {
    int lin = i * 256 + tid;            // 16B-bf16 chunk id, 0..2047
    int r = lin >> 5, cc = lin & 31;
    int dst = r * 512 + ((cc ^ (r & 7)) << 4);
    f32x4 a = *(const f32x4*)(xsrc + lin * 8);
    f32x4 b = *(const f32x4*)(xsrc + lin * 8 + 4);
    u32x4 pk;
    pk[0] = cvtpk(a[0], a[1]); pk[1] = cvtpk(a[2], a[3]);
    pk[2] = cvtpk(b[0], b[1]); pk[3] = cvtpk(b[2], b[3]);
    *(u32x4*)(xs + dst) = pk;
    *(s16x8*)(wsl + dst) = *(const s16x8*)(wqh + lin * 8);  // chunk 0 = wq cols 0..63
  }
  __syncthreads();

  for (int c = 0; c < 12; ++c) {
    int seg = c >> 2, h = c & 3, nb0 = h * 64;
    const float* bias = seg == 0 ? bq : (seg == 1 ? bk : bv);

    // prefetch next chunk's W slice into regs (hides under this chunk's compute)
    s16x8 gw[8];
    if (c < 11) {
      int cn = c + 1, segn = cn >> 2;
      const unsigned short* wn = (segn == 0 ? wqh : segn == 1 ? wkh : wvh) + (size_t)(cn & 3) * 64 * DIN;
#pragma unroll
      for (int i = 0; i < 8; ++i) gw[i] = *(const s16x8*)(wn + (i * 256 + tid) * 8);
    }

    f32x4 acc[4] = {};
    if (seg < 2) {
      int chrow = wave * 16 + lr;       // A = W row (output channel)
#pragma unroll
      for (int k0 = 0; k0 < 8; ++k0) {
        int cg = k0 * 4 + lk;
        s16x8 a = *(const s16x8*)(wsl + chrow * 512 + ((cg ^ (chrow & 7)) << 4));
#pragma unroll
        for (int ct = 0; ct < 4; ++ct) {
          int tr = ct * 16 + lr;
          s16x8 b = *(const s16x8*)(xs + tr * 512 + ((cg ^ (tr & 7)) << 4));
          mfma16(acc[ct], a, b);
        }
      }
      unsigned short* dst = (seg == 0) ? Qb : Kb;
      f32x4 bv4 = *(const f32x4*)(bias + nb0 + wave * 16 + lk * 4);
#pragma unroll
      for (int ct = 0; ct < 4; ++ct) {
        int n_ = t0 + ct * 16 + lr;
        int b_ = n_ >> 9, nn = n_ & 511;
        u16x4 pk;
#pragma unroll
        for (int j = 0; j < 4; ++j) pk[j] = f2b(acc[ct][j] + bv4[j]);
        *(u16x4*)(dst + ((size_t)(b_ * HH + h) * NN + nn) * HD + wave * 16 + lk * 4) = pk;
      }
    } else {
      int tokrow = wave * 16 + lr;      // A = x row (token)
#pragma unroll
      for (int k0 = 0; k0 < 8; ++k0) {
        int cg = k0 * 4 + lk;
        s16x8 a = *(const s16x8*)(xs + tokrow * 512 + ((cg ^ (tokrow & 7)) << 4));
#pragma unroll
        for (int nt = 0; nt < 4; ++nt) {
          int cr = nt * 16 + lr;
          s16x8 b = *(const s16x8*)(wsl + cr * 512 + ((cg ^ (cr & 7)) << 4));
          mfma16(acc[nt], a, b);
        }
      }
      int m0 = t0 + wave * 16 + lk * 4;
      int b_ = m0 >> 9, n0 = m0 & 511;
#pragma unroll
      for (int nt = 0; nt < 4; ++nt) {
        int hd = nt * 16 + lr;
        float bs = bias[nb0 + hd];
        u16x4 pk;
#pragma unroll
        for (int j = 0; j < 4; ++j) pk[j] = f2b(acc[nt][j] + bs);
        *(u16x4*)(Vtb + ((size_t)(b_ * HH + h) * HD + hd) * NN + n0) = pk;
      }
    }
    __syncthreads();                    // all waves done reading wsl
    if (c < 11) {
#pragma unroll
      for (int i = 0; i < 8; ++i) {
        int lin = i * 256 + tid;
        int r = lin >> 5, cc = lin & 31;
        *(s16x8*)(wsl + r * 512 + ((cc ^ (r & 7)) << 4)) = gw[i];
      }
    }
    __syncthreads();                    // wsl ready for next chunk
  }
}

// ---------------- attention (unchanged from measured round 10) ----------------
__global__ __launch_bounds__(512, 2) void k_attn(
    const unsigned short* __restrict__ Qb, const unsigned short* __restrict__ Kb,
    const unsigned short* __restrict__ Vtb, const unsigned long long* __restrict__ ab,
    unsigned short* __restrict__ att)
{
  __shared__ __align__(16) unsigned char kl[2][8192];   // K tiles, XOR-swizzled
  __shared__ __align__(16) unsigned char vtl[2][8192];  // Vt tiles, XOR-swizzled
  __shared__ __align__(16) unsigned char plb[32768];    // per-wave P [2 sub][16 q][64 keys]

  int tid = threadIdx.x, wave = tid >> 6, lane = tid & 63;
  int lr = lane & 15, lk = lane >> 4;
  int bid = blockIdx.x;
  int g = bid >> 4, r = bid & 15;
  int bh = g * 8 + (r & 7);     // pair of blocks sharing bh differ by 8 -> same XCD
  int qt = r >> 3;
  int h = bh & 3, b_ = bh >> 2;
  const unsigned short* Qp = Qb + (size_t)bh * NN * HD;
  const unsigned short* Kp = Kb + (size_t)bh * NN * HD;
  const unsigned short* Vp = Vtb + (size_t)bh * HD * NN;
  int q0 = qt * 256 + wave * 32;

  s16x8 qa[2][2];
#pragma unroll
  for (int s = 0; s < 2; ++s) {
    qa[s][0] = *(const s16x8*)(Qp + (q0 + s * 16 + lr) * HD + lk * 8);
    qa[s][1] = *(const s16x8*)(Qp + (q0 + s * 16 + lr) * HD + 32 + lk * 8);
  }

  f32x4 oacc[2][4] = {};
  float rs[2] = {0.f, 0.f};
  unsigned char* plw = plb + wave * 4096;
  int sw = (lr & 7) << 4;

  int srow = tid >> 3, scol = tid & 7;
  int sdst = srow * 128 + ((scol * 16) ^ ((srow & 7) << 4));
  const unsigned short* ksrc = Kp + srow * HD + scol * 8;
  const unsigned short* vsrc = Vp + srow * NN + scol * 8;

  // prologue: stage kt=0
  *(s16x8*)(kl[0] + sdst)  = *(const s16x8*)ksrc;
  *(s16x8*)(vtl[0] + sdst) = *(const s16x8*)vsrc;
  __syncthreads();

#pragma unroll
  for (int kt = 0; kt < 8; ++kt) {
    unsigned char* klc = kl[kt & 1];
    unsigned char* vtc = vtl[kt & 1];
    unsigned long long abr[2];
#pragma unroll
    for (int s = 0; s < 2; ++s) abr[s] = ab[(size_t)(q0 + s * 16 + lr) * 8 + kt];

    // ---- QK^T + softmax-exp + P store (gk/gv not yet live) ----
#pragma unroll
    for (int s = 0; s < 2; ++s) {
#pragma unroll
      for (int ks = 0; ks < 4; ++ks) {
        int key = ks * 16 + lr;
        s16x8 kb0 = *(const s16x8*)(klc + key * 128 + ((lk * 16) ^ ((key & 7) << 4)));
        s16x8 kb1 = *(const s16x8*)(klc + key * 128 + ((64 + lk * 16) ^ ((key & 7) << 4)));
        f32x4 sx = {};
        mfma16(sx, kb0, qa[s][0]);   // S^T: rows key=16ks+4lk+j, col q=lr
        mfma16(sx, kb1, qa[s][1]);
        float p[4];
#pragma unroll
        for (int j = 0; j < 4; ++j)
          p[j] = ((abr[s] >> (ks * 16 + lk * 4 + j)) & 1ULL) ? __expf(sx[j] * 0.125f) : 0.0f;
        unsigned w0 = cvtpk(p[0], p[1]);
        unsigned w1 = cvtpk(p[2], p[3]);
        union { unsigned u; float f; } t0, t1, t2, t3;
        t0.u = w0 << 16; t1.u = w0 & 0xffff0000u;
        t2.u = w1 << 16; t3.u = w1 & 0xffff0000u;
        rs[s] += (t0.f + t1.f) + (t2.f + t3.f);
        uint2 pw; pw.x = w0; pw.y = w1;
        *(uint2*)(plw + s * 2048 + lr * 128 + ((ks * 32 + lk * 8) ^ sw)) = pw;
      }
    }

    // ---- issue next-tile prefetch; latency hides under PV below ----
    s16x8 gk, gv;
    if (kt < 7) {
      gk = *(const s16x8*)(ksrc + (kt + 1) * 64 * HD);
      gv = *(const s16x8*)(vsrc + (kt + 1) * 64);
    }

    // ---- PV (P wave-private: compiler orders plb store->load via lgkmcnt) ----
#pragma unroll
    for (int s = 0; s < 2; ++s) {
      s16x8 pa0 = *(const s16x8*)(plw + s * 2048 + lr * 128 + ((lk * 16) ^ sw));
      s16x8 pa1 = *(const s16x8*)(plw + s * 2048 + lr * 128 + ((64 + lk * 16) ^ sw));
#pragma unroll
      for (int dt = 0; dt < 4; ++dt) {
        int d = dt * 16 + lr;
        s16x8 vb0 = *(const s16x8*)(vtc + d * 128 + ((lk * 16) ^ ((d & 7) << 4)));
        s16x8 vb1 = *(const s16x8*)(vtc + d * 128 + ((64 + lk * 16) ^ ((d & 7) << 4)));
        mfma16(oacc[s][dt], vb0, pa0);  // O^T: rows d=dt*16+4lk+j, col q=lr
        mfma16(oacc[s][dt], vb1, pa1);
      }
    }
    if (kt < 7) {
      *(s16x8*)(kl[(kt & 1) ^ 1] + sdst)  = gk;
      *(s16x8*)(vtl[(kt & 1) ^ 1] + sdst) = gv;
      __syncthreads();
    }
  }

#pragma unroll
  for (int s = 0; s < 2; ++s) {
    float v = rs[s];
    v += __shfl_xor(v, 16);
    v += __shfl_xor(v, 32);
    float rinv = 1.0f / v;
    int n_ = q0 + s * 16 + lr;
#pragma unroll
    for (int dt = 0; dt < 4; ++dt) {
      uint2 ow;
      ow.x = cvtpk(oacc[s][dt][0] * rinv, oacc[s][dt][1] * rinv);
      ow.y = cvtpk(oacc[s][dt][2] * rinv, oacc[s][dt][3] * rinv);
      *(uint2*)(att + ((size_t)(b_ * NN + n_) * DOUT) + h * HD + dt * 16 + lk * 4) = ow;
    }
  }
}

// ---------------- output projection (att staged ONCE, 4 chunk loop) ----------------
// grid 512: block = 64-token att-tile; loops 4 out-col chunks, wo reg-prefetched.
__global__ __launch_bounds__(256, 2) void k_out(
    const unsigned short* __restrict__ att, const unsigned short* __restrict__ woh,
    const float* __restrict__ bo, float* __restrict__ out)
{
  __shared__ __align__(16) unsigned char as_[32768];
  __shared__ __align__(16) unsigned char wsl[32768];
  int tid = threadIdx.x, wave = tid >> 6, lane = tid & 63;
  int lr = lane & 15, lk = lane >> 4;
  int t0 = blockIdx.x * 64;

  const unsigned short* asrc = att + (size_t)t0 * DOUT;
#pragma unroll
  for (int i = 0; i < 8; ++i) {
    int lin = i * 256 + tid;
    int r = lin >> 5, cc = lin & 31;
    int dst = r * 512 + ((cc ^ (r & 7)) << 4);
    *(s16x8*)(as_ + dst) = *(const s16x8*)(asrc + lin * 8);
    *(s16x8*)(wsl + dst) = *(const s16x8*)(woh + lin * 8);  // chunk 0
  }
  __syncthreads();

  for (int c = 0; c < 4; ++c) {
    int nb0 = c * 64;
    s16x8 gw[8];
    if (c < 3) {
      const unsigned short* wn = woh + (size_t)(c + 1) * 64 * DOUT;
#pragma unroll
      for (int i = 0; i < 8; ++i) gw[i] = *(const s16x8*)(wn + (i * 256 + tid) * 8);
    }

    f32x4 acc[4] = {};
    int chrow = wave * 16 + lr;
#pragma unroll
    for (int k0 = 0; k0 < 8; ++k0) {
      int cg = k0 * 4 + lk;
      s16x8 a = *(const s16x8*)(wsl + chrow * 512 + ((cg ^ (chrow & 7)) << 4));
#pragma unroll
      for (int ct = 0; ct < 4; ++ct) {
        int tr = ct * 16 + lr;
        s16x8 b = *(const s16x8*)(as_ + tr * 512 + ((cg ^ (tr & 7)) << 4));
        mfma16(acc[ct], a, b);
      }
    }
    f32x4 bv4 = *(const f32x4*)(bo + nb0 + wave * 16 + lk * 4);
#pragma unroll
    for (int ct = 0; ct < 4; ++ct) {
      int m = t0 + ct * 16 + lr;
      f32x4 o = acc[ct] + bv4;
      *(f32x4*)(out + (size_t)m * DOUT + nb0 + wave * 16 + lk * 4) = o;
    }
    __syncthreads();
    if (c < 3) {
#pragma unroll
      for (int i = 0; i < 8; ++i) {
        int lin = i * 256 + tid;
        int r = lin >> 5, cc = lin & 31;
        *(s16x8*)(wsl + r * 512 + ((cc ^ (r & 7)) << 4)) = gw[i];
      }
    }
    __syncthreads();
  }
}

extern "C" void kernel_launch(void* const* d_in, const int* in_sizes, int n_in,
                              void* d_out, int out_size, void* d_ws, size_t ws_size,
                              hipStream_t stream) {
  const float* x  = (const float*)d_in[0];
  const int*   adj = (const int*)d_in[1];
  const float* wq = (const float*)d_in[2];
  const float* bq = (const float*)d_in[3];
  const float* wk = (const float*)d_in[4];
  const float* bk = (const float*)d_in[5];
  const float* wv = (const float*)d_in[6];
  const float* bv = (const float*)d_in[7];
  const float* wo = (const float*)d_in[8];
  const float* bo = (const float*)d_in[9];
  float* out = (float*)d_out;

  char* ws = (char*)d_ws;
  size_t off = 0;
  auto carve = [&](size_t bytes) -> char* {
    off = (off + 255) & ~(size_t)255;
    char* p = ws + off;
    off += bytes;
    return p;
  };
  unsigned short* wqh  = (unsigned short*)carve((size_t)DOUT * DIN * 2);
  unsigned short* wkh  = (unsigned short*)carve((size_t)DOUT * DIN * 2);
  unsigned short* wvh  = (unsigned short*)carve((size_t)DOUT * DIN * 2);
  unsigned short* woh  = (unsigned short*)carve((size_t)DOUT * DOUT * 2);
  unsigned long long* abits = (unsigned long long*)carve((size_t)NN * 8 * 8);
  unsigned short* Qb   = (unsigned short*)carve((size_t)BB * HH * NN * HD * 2);
  unsigned short* Kb   = (unsigned short*)carve((size_t)BB * HH * NN * HD * 2);
  unsigned short* Vtb  = (unsigned short*)carve((size_t)BB * HH * HD * NN * 2);
  unsigned short* attb = (unsigned short*)carve((size_t)BB * NN * DOUT * 2);

  k_wconv<<<dim3(256), 256, 0, stream>>>(wq, wk, wv, wo, wqh, wkh, wvh, woh);
  k_adjbits<<<dim3(512), 512, 0, stream>>>(adj, abits);
  k_qkv<<<dim3(512), 256, 0, stream>>>(x, wqh, wkh, wvh, bq, bk, bv, Qb, Kb, Vtb);
  k_attn<<<dim3(512), 512, 0, stream>>>(Qb, Kb, Vtb, abits, attb);
  k_out<<<dim3(512), 256, 0, stream>>>(attb, woh, bo, out);
}